// Round 4
// baseline (794.281 us; speedup 1.0000x reference)
//
#include <hip/hip_runtime.h>
#include <hip/hip_bf16.h>
#include <type_traits>

constexpr int B  = 16;
constexpr int C  = 128;
constexpr int H  = 128;
constexpr int W  = 128;
constexpr int CO = 256;
constexpr int HO = 64;
constexpr int WO = 64;

#define EPSV   1e-8f
#define SLOPE  0.2f

typedef short bf16x8 __attribute__((ext_vector_type(8)));
typedef float f32x4  __attribute__((ext_vector_type(4)));

__device__ __forceinline__ short f2bs(float v) {
    __hip_bfloat16 h = __float2bfloat16(v);
    return *(short*)&h;
}
__device__ __forceinline__ float bs2f(short s) {
    __hip_bfloat16 h = *(__hip_bfloat16*)&s;
    return __bfloat162float(h);
}

// ---------------------------------------------------------------------------
// fused demod+expand: block = (conv,b,oc); computes d then writes 9 taps.
// wm[cb][tap][ocT][icC][(oc&15)*32+(ic&31)]
// ---------------------------------------------------------------------------
__global__ __launch_bounds__(128) void demod_expand_kernel(
    const float* __restrict__ w1, const float* __restrict__ w2,
    const float* __restrict__ s1, const float* __restrict__ s2,
    short* __restrict__ wm)
{
    int bid  = blockIdx.x;          // conv*2048 + b*128 + oc
    int conv = bid >> 11;
    int cb   = bid >> 7;            // conv*16 + b
    int oc   = bid & 127;
    int b    = cb & 15;
    const float* w = conv ? w2 : w1;
    const float* s = conv ? s2 : s1;
    int ic = threadIdx.x;
    float sv = s[b * C + ic] + 1.0f;
    const float* wp = w + (oc * C + ic) * 9;
    float wl[9], sum = 0.f;
    #pragma unroll
    for (int k = 0; k < 9; ++k) { wl[k] = wp[k]; float t = wl[k] * sv; sum += t * t; }
    #pragma unroll
    for (int off = 32; off; off >>= 1) sum += __shfl_down(sum, off);
    __shared__ float red[2];
    __shared__ float dsh;
    if ((ic & 63) == 0) red[ic >> 6] = sum;
    __syncthreads();
    if (ic == 0) dsh = rsqrtf(red[0] + red[1] + EPSV);
    __syncthreads();
    float dval = dsh;
    int base = cb * 147456 + ((oc >> 4) * 4 + (ic >> 5)) * 512
             + (oc & 15) * 32 + (ic & 31);
    #pragma unroll
    for (int tap = 0; tap < 9; ++tap)
        wm[base + tap * 16384] = f2bs(wl[tap] * sv * dval);
}

// ---------------------------------------------------------------------------
// dwexpand: dwm[tap][ocT(16)][icC(4)][(oc&15)*32+(ic&31)]
// ---------------------------------------------------------------------------
__global__ __launch_bounds__(256) void dwexpand_kernel(
    const float* __restrict__ dw, short* __restrict__ dwm)
{
    int idx = blockIdx.x * 256 + threadIdx.x;   // 524288
    int ic  = idx & 127;
    int oc  = (idx >> 7) & 255;
    int tap = idx >> 15;
    int dst = ((tap * 16 + (oc >> 4)) * 4 + (ic >> 5)) * 512
            + (oc & 15) * 32 + (ic & 31);
    dwm[dst] = f2bs(dw[(oc * C + ic) * 16 + tap]);
}

// ---------------------------------------------------------------------------
// conv3x3 MFMA implicit GEMM, register-double-buffered K pipeline.
// block tile: 128 px (8h x 16w) x 128 oc; wave: 64 px x 64 oc.
// InT=float: stage directly from NCHW fp32 (fused transpose).
// QUAD: write parity-quadrant layout [b][h&1][w&1][h/2][w/2][C] for downconv.
// blockIdx swizzled so (blockIdx & 7) == (b & 7)  [XCD L2 locality]
// ---------------------------------------------------------------------------
template <typename InT, bool QUAD, bool RES>
__global__ __launch_bounds__(256, 3) void conv3x3_mfma(
    const InT* __restrict__ in, const short* __restrict__ wmc,
    const short* __restrict__ res, short* __restrict__ out)
{
    __shared__ short sIn[10 * 18 * 136];   // 48,960 B

    int s = blockIdx.x;                    // swizzle: b low 3 bits -> XCD
    int b = (s & 7) | (((s >> 10) & 1) << 3);
    int t = (s >> 3) & 127;
    int wt = t & 7, ht = t >> 3;
    int w0 = wt * 16, h0 = ht * 8;

    int tid  = threadIdx.x;
    int lane = tid & 63, wv = tid >> 6;
    int q = lane >> 4, l15 = lane & 15;
    int wr = wv & 1;       // row half
    int wc = wv >> 1;      // oc half

    if constexpr (std::is_same<InT, float>::value) {
        // NCHW fp32 staging (fused transpose): 128ic x 10r x 18c
        for (int i = tid; i < 128 * 180; i += 256) {
            int ic  = i / 180;
            int rem = i - ic * 180;
            int r = rem / 18, cc = rem - r * 18;
            int gh = h0 - 1 + r, gw = w0 - 1 + cc;
            float v = 0.f;
            if ((unsigned)gh < (unsigned)H && (unsigned)gw < (unsigned)W)
                v = in[((b * C + ic) * H + gh) * W + gw];
            sIn[(r * 18 + cc) * 136 + ic] = f2bs(v);
        }
    } else {
        for (int i = tid; i < 10 * 18 * 16; i += 256) {
            int icg = i & 15;
            int t2 = i >> 4;
            int wl = t2 % 18, hl = t2 / 18;
            int gh = h0 - 1 + hl, gw = w0 - 1 + wl;
            uint4 v = make_uint4(0u, 0u, 0u, 0u);
            if ((unsigned)gh < (unsigned)H && (unsigned)gw < (unsigned)W)
                v = *(const uint4*)&in[((b * H + gh) * W + gw) * C + icg * 8];
            *(uint4*)&sIn[(hl * 18 + wl) * 136 + icg * 8] = v;
        }
    }
    __syncthreads();

    const short* wb = wmc + b * 147456;

    f32x4 acc[4][4];
    #pragma unroll
    for (int mt = 0; mt < 4; ++mt)
        #pragma unroll
        for (int nt = 0; nt < 4; ++nt)
            acc[mt][nt] = (f32x4){0.f, 0.f, 0.f, 0.f};

    bf16x8 af[2][4], bf[2][4];

    #pragma unroll
    for (int mt = 0; mt < 4; ++mt)
        af[0][mt] = *(const bf16x8*)&sIn[((wr * 4 + mt) * 18 + l15) * 136 + q * 8];
    #pragma unroll
    for (int nt = 0; nt < 4; ++nt)
        bf[0][nt] = *(const bf16x8*)&wb[((wc * 4 + nt) * 4) * 512 + l15 * 32 + q * 8];

    #pragma unroll 1
    for (int tap = 0; tap < 9; ++tap) {
        int dh  = tap / 3,  dwd = tap - dh * 3;
        int tapn = (tap + 1 < 9) ? tap + 1 : tap;
        int dhn = tapn / 3, dwn = tapn - dhn * 3;
        #pragma unroll
        for (int c = 0; c < 4; ++c) {
            int p  = c & 1, pn = p ^ 1;
            int cn = (c + 1) & 3;
            int tE  = (c == 3) ? tapn : tap;
            int dhE = (c == 3) ? dhn : dh;
            int dwE = (c == 3) ? dwn : dwd;
            #pragma unroll
            for (int mt = 0; mt < 4; ++mt)
                af[pn][mt] = *(const bf16x8*)&sIn[((wr * 4 + mt + dhE) * 18 + l15 + dwE) * 136
                                                  + cn * 32 + q * 8];
            #pragma unroll
            for (int nt = 0; nt < 4; ++nt)
                bf[pn][nt] = *(const bf16x8*)&wb[((tE * 8 + wc * 4 + nt) * 4 + cn) * 512
                                                 + l15 * 32 + q * 8];
            #pragma unroll
            for (int mt = 0; mt < 4; ++mt)
                #pragma unroll
                for (int nt = 0; nt < 4; ++nt)
                    acc[mt][nt] = __builtin_amdgcn_mfma_f32_16x16x32_bf16(
                        af[p][mt], bf[p][nt], acc[mt][nt], 0, 0, 0);
        }
    }

    #pragma unroll
    for (int mt = 0; mt < 4; ++mt) {
        int h = h0 + wr * 4 + mt;
        #pragma unroll
        for (int nt = 0; nt < 4; ++nt) {
            int oc = wc * 64 + nt * 16 + l15;
            #pragma unroll
            for (int reg = 0; reg < 4; ++reg) {
                int w = w0 + q * 4 + reg;
                float v = acc[mt][nt][reg];
                if constexpr (RES) v += bs2f(res[((b * H + h) * W + w) * C + oc]);
                v = v >= 0.f ? v : SLOPE * v;
                if constexpr (QUAD) {
                    int qb = (b * 2 + (h & 1)) * 2 + (w & 1);
                    out[((qb * 64 + (h >> 1)) * 64 + (w >> 1)) * 128 + oc] = f2bs(v);
                } else {
                    out[((b * H + h) * W + w) * C + oc] = f2bs(v);
                }
            }
        }
    }
}

// ---------------------------------------------------------------------------
// downconv via parity quadrants: 4 phases (hp,wp), each a unit-stride 2x2 conv
// on a 9x17 halo tile of plane [b][hp][wp][64][64][128].
// block tile: 128 out px (8oh x 16ow) x 128 oc; wave: 64oc x 64px.
// A = weights dwm (global), B = input tile (LDS). D: row=oc, col=ow.
// ---------------------------------------------------------------------------
__global__ __launch_bounds__(256, 3) void downconv_mfma(
    const short* __restrict__ xq, const short* __restrict__ dwm,
    const float* __restrict__ db, float* __restrict__ out)
{
    __shared__ short sT[9 * 17 * 136];   // 41,616 B

    int s = blockIdx.x;                  // swizzle: b low 3 bits -> XCD
    int b = (s & 7) | (((s >> 9) & 1) << 3);
    int t = (s >> 3) & 63;
    int wt = t & 3, ht = (t >> 2) & 7, ot = t >> 5;
    int ow0 = wt * 16, oh0 = ht * 8, oc0 = ot * 128;

    int tid  = threadIdx.x;
    int lane = tid & 63, wv = tid >> 6;
    int q = lane >> 4, l15 = lane & 15;
    int wo = wv & 1;     // oc half
    int wp = wv >> 1;    // oh half
    int ocTb = ot * 8 + wo * 4;

    f32x4 acc[4][4];     // [mt = oc tile][nt = oh row]
    #pragma unroll
    for (int mt = 0; mt < 4; ++mt)
        #pragma unroll
        for (int nt = 0; nt < 4; ++nt)
            acc[mt][nt] = (f32x4){0.f, 0.f, 0.f, 0.f};

    #pragma unroll 1
    for (int ph = 0; ph < 4; ++ph) {
        int hp = ph >> 1, wpar = ph & 1;
        int dhb = 1 - hp, dwb = 1 - wpar;        // tap base parity offset
        int oh_org = oh0 - hp, ow_org = ow0 - wpar;
        int qbase = (b * 2 + hp) * 2 + wpar;

        __syncthreads();
        for (int i = tid; i < 9 * 17 * 16; i += 256) {
            int icg = i & 15;
            int t2 = i >> 4;
            int cc = t2 % 17, r = t2 / 17;
            int h2 = oh_org + r, w2 = ow_org + cc;
            uint4 v = make_uint4(0u, 0u, 0u, 0u);
            if ((unsigned)h2 < 64u && (unsigned)w2 < 64u)
                v = *(const uint4*)&xq[((qbase * 64 + h2) * 64 + w2) * 128 + icg * 8];
            *(uint4*)&sT[(r * 17 + cc) * 136 + icg * 8] = v;
        }
        __syncthreads();

        bf16x8 af[2][4], bf[2][4];
        // prologue step 0: tap2h=0, tap2w=0, c=0
        {
            int tap = (2 * 0 + dhb) * 4 + (2 * 0 + dwb);
            #pragma unroll
            for (int mt = 0; mt < 4; ++mt)
                af[0][mt] = *(const bf16x8*)&dwm[((tap * 16 + ocTb + mt) * 4) * 512
                                                 + l15 * 32 + q * 8];
            #pragma unroll
            for (int nt = 0; nt < 4; ++nt)
                bf[0][nt] = *(const bf16x8*)&sT[((wp * 4 + nt) * 17 + l15) * 136 + q * 8];
        }

        #pragma unroll
        for (int s2 = 0; s2 < 16; ++s2) {
            int p = s2 & 1, pn = p ^ 1;
            int s2n = (s2 + 1 < 16) ? s2 + 1 : s2;
            int tln = s2n >> 2, cn = s2n & 3;
            int t2hn = tln >> 1, t2wn = tln & 1;
            int tapn = (2 * t2hn + dhb) * 4 + (2 * t2wn + dwb);
            // prefetch step s2+1
            #pragma unroll
            for (int mt = 0; mt < 4; ++mt)
                af[pn][mt] = *(const bf16x8*)&dwm[((tapn * 16 + ocTb + mt) * 4 + cn) * 512
                                                  + l15 * 32 + q * 8];
            #pragma unroll
            for (int nt = 0; nt < 4; ++nt)
                bf[pn][nt] = *(const bf16x8*)&sT[((wp * 4 + nt + t2hn) * 17 + l15 + t2wn) * 136
                                                 + cn * 32 + q * 8];
            // compute step s2
            #pragma unroll
            for (int mt = 0; mt < 4; ++mt)
                #pragma unroll
                for (int nt = 0; nt < 4; ++nt)
                    acc[mt][nt] = __builtin_amdgcn_mfma_f32_16x16x32_bf16(
                        af[p][mt], bf[p][nt], acc[mt][nt], 0, 0, 0);
        }
    }

    #pragma unroll
    for (int mt = 0; mt < 4; ++mt) {
        #pragma unroll
        for (int reg = 0; reg < 4; ++reg) {
            int oc = oc0 + wo * 64 + mt * 16 + q * 4 + reg;
            float bias = db[oc];
            #pragma unroll
            for (int nt = 0; nt < 4; ++nt) {
                int oh = oh0 + wp * 4 + nt;
                int ow = ow0 + l15;
                out[((b * CO + oc) * HO + oh) * WO + ow] = acc[mt][nt][reg] + bias;
            }
        }
    }
}

// ---------------------------------------------------------------------------
extern "C" void kernel_launch(void* const* d_in, const int* in_sizes, int n_in,
                              void* d_out, int out_size, void* d_ws, size_t ws_size,
                              hipStream_t stream) {
    const float* features = (const float*)d_in[0];
    const float* sm1      = (const float*)d_in[1];   // style_mean1 -> s1
    const float* ss1      = (const float*)d_in[2];   // style_std1  -> s2 (per reference)
    const float* w1       = (const float*)d_in[6];
    const float* w2       = (const float*)d_in[7];
    const float* dw       = (const float*)d_in[8];
    const float* db       = (const float*)d_in[9];
    float* out = (float*)d_out;

    char* ws = (char*)d_ws;
    short* x1  = (short*)ws;                              // 67,108,864 B (NHWC)
    short* x2q = (short*)(ws + 67108864);                 // 67,108,864 B (quadrants)
    short* wm  = (short*)(ws + 134217728);                // 9,437,184 B
    short* dwm = (short*)(ws + 143654912);                // 1,048,576 B

    demod_expand_kernel<<<4096, 128, 0, stream>>>(w1, w2, sm1, ss1, wm);
    dwexpand_kernel    <<<2048, 256, 0, stream>>>(dw, dwm);
    conv3x3_mfma<float, false, false><<<2048, 256, 0, stream>>>(features, wm, nullptr, x1);
    conv3x3_mfma<short, true,  true ><<<2048, 256, 0, stream>>>(x1, wm + 16 * 147456, x1, x2q);
    downconv_mfma      <<<1024, 256, 0, stream>>>(x2q, dwm, db, out);
}